// Round 1
// baseline (917.452 us; speedup 1.0000x reference)
//
#include <hip/hip_runtime.h>
#include <hip/hip_bf16.h>

#define BN 8
#define HN 128
#define WN 128
#define CN 256
#define DTC 0.2f
#define EPSV 1e-3f
#define NTH 1024

#define SW 136     // s0s w-stride (halfs): col0/col129 zero pads, data 1..128, 130..135 unused (16B row align)
#define HBS 132    // h-buffer row stride (floats): 132 ≡ 4 mod 32 banks → de-conflicts pass-5 column reads

// ---- dtype-generic helpers (compute stays f32) ----
__device__ __forceinline__ float ldf(const float* p)            { return *p; }
__device__ __forceinline__ float ldf(const __hip_bfloat16* p)   { return __bfloat162float(*p); }
__device__ __forceinline__ void stf(float* p, float v)          { *p = v; }
__device__ __forceinline__ void stf(__hip_bfloat16* p, float v) { *p = __float2bfloat16(v); }

// packed bf16 extraction (exact f32)
__device__ __forceinline__ float lo16(unsigned u){ return __uint_as_float(u << 16); }
__device__ __forceinline__ float hi16(unsigned u){ return __uint_as_float(u & 0xffff0000u); }

// stage 4 consecutive channels (one vector load) into 4 LDS channel-rows
__device__ __forceinline__ void stage4(__hip_bfloat16* dp, const __hip_bfloat16* gp) {
    ushort4 v = *reinterpret_cast<const ushort4*>(gp);
    unsigned short* d = reinterpret_cast<unsigned short*>(dp);
    d[0] = v.x; d[SW] = v.y; d[2*SW] = v.z; d[3*SW] = v.w;
}
__device__ __forceinline__ void stage4(__hip_bfloat16* dp, const float* gp) {
    float4 v = *reinterpret_cast<const float4*>(gp);
    dp[0]    = __float2bfloat16(v.x);
    dp[SW]   = __float2bfloat16(v.y);
    dp[2*SW] = __float2bfloat16(v.z);
    dp[3*SW] = __float2bfloat16(v.w);
}

// ---- dtype probe: bf16 exponent band test on raw u32 words ----
__global__ void probe_kernel(const unsigned int* __restrict__ s0w, int* __restrict__ flag) {
    __shared__ int cnt;
    if (threadIdx.x == 0) cnt = 0;
    __syncthreads();
    int local = 0;
    for (int i = threadIdx.x; i < 4096; i += 256) {
        unsigned int e = (s0w[i] >> 7) & 0xFF;
        if (e >= 118 && e <= 130) local++;
    }
    atomicAdd(&cnt, local);
    __syncthreads();
    if (threadIdx.x == 0) *flag = (cnt > 2048) ? 1 : 0;   // 1 = bf16, 0 = f32
}

template <typename T>
__global__ __launch_bounds__(NTH, 8)
void diffusion_kernel(const T* __restrict__ s0,  const T* __restrict__ wg,  const T* __restrict__ wg1,
                      const T* __restrict__ g_gamma,  const T* __restrict__ g_beta,
                      const T* __restrict__ g_mean,   const T* __restrict__ g_var,
                      const T* __restrict__ g1_gamma, const T* __restrict__ g1_beta,
                      const T* __restrict__ g1_mean,  const T* __restrict__ g1_var,
                      const T* __restrict__ out_gamma, const T* __restrict__ out_beta,
                      const T* __restrict__ out_mean,  const T* __restrict__ out_var,
                      T* __restrict__ out,
                      const int* __restrict__ flag, int want)
{
    if (flag && *flag != want) return;   // dtype dispatch

    __shared__ __align__(16) __hip_bfloat16 s0s[3][32][SW];  // 26112 B
    __shared__ float wgt[2][9][32];                          //  2304 B
    __shared__ float bnp[4][32];                             //   512 B
    __shared__ float obn[2][16];                             //   128 B
    __shared__ __align__(16) float g1b[28*128];              // 14336 B
    __shared__ __align__(16) float hb0[28*HBS];              // 14784 B
    __shared__ __align__(16) float hb1[28*HBS];              // 14784 B
    // total 72960 B -> 2 blocks/CU

    const int tid = threadIdx.x;
    const int bid = blockIdx.x;
    const int h     = bid & 127;
    const int bc    = bid >> 7;
    const int chunk = bc & 15;
    const int b     = bc >> 4;
    const int c0    = chunk << 4;

    const int   rT   = (h > 0)   ? h - 1 : 1;      // sobel reflect rows
    const int   rB   = (h < 127) ? h + 1 : 126;
    const float topf = (h > 0)   ? 1.f : 0.f;      // conv zero-pad flags (folded into weights)
    const float botf = (h < 127) ? 1.f : 0.f;

    // ---- stage s0: 3 rows x 32 ch x 128 w; 4-channel vector loads (3072 total, 3/thread) ----
    {
        const size_t base = (size_t)b * HN * WN * CN;
        #pragma unroll
        for (int k = 0; k < 3; ++k) {
            int e  = tid + k * NTH;                // < 3072
            int j4 = e & 7;                        // 4-channel group
            int w  = (e >> 3) & 127;
            int r  = e >> 10;                      // 0..2
            int row = (r == 0) ? rT : ((r == 1) ? h : rB);
            int cj  = (c0 - 8 + (j4 << 2)) & 255;  // group never straddles the wrap (4-aligned)
            stage4(&s0s[r][j4 << 2][w + 1], &s0[base + ((size_t)row * WN + w) * CN + cj]);
        }
    }
    if (tid < 192) {                               // zero pad columns (conv SAME)
        int r = tid >> 6, j = (tid >> 1) & 31, cp = (tid & 1) ? 129 : 0;
        s0s[r][j][cp] = __float2bfloat16(0.f);
    }
    if (tid < 288) {                               // weights, H-pad folded in
        int t9 = tid >> 5, j = tid & 31;
        int cj = (c0 - 8 + j) & 255;
        float rf = (t9 < 3) ? topf : ((t9 >= 6) ? botf : 1.f);
        wgt[0][t9][j] = ldf(&wg [t9*CN + cj]) * rf;
        wgt[1][t9][j] = ldf(&wg1[t9*CN + cj]) * rf;
    }
    if (tid < 32) {                                // folded BN params
        int cj = (c0 - 8 + tid) & 255;
        float s  = ldf(&g_gamma[cj])  * rsqrtf(ldf(&g_var[cj])  + EPSV);
        bnp[0][tid] = s;
        bnp[1][tid] = ldf(&g_beta[cj])  - ldf(&g_mean[cj])  * s;
        float s1 = ldf(&g1_gamma[cj]) * rsqrtf(ldf(&g1_var[cj]) + EPSV);
        bnp[2][tid] = s1;
        bnp[3][tid] = ldf(&g1_beta[cj]) - ldf(&g1_mean[cj]) * s1;
    }
    if (tid < 16) {
        int c = c0 + tid;
        float s = ldf(&out_gamma[c]) * rsqrtf(ldf(&out_var[c]) + EPSV);
        obn[0][tid] = s;
        obn[1][tid] = ldf(&out_beta[c]) - ldf(&out_mean[c]) * s;
    }
    __syncthreads();   // B1

    // thread geometry: half-wave = one channel row, wq = quad index in W
    const int wq = tid & 31, l = tid >> 5, w0 = wq << 2;
    const int lane = tid & 63;
    const int sL = (lane & 32) | ((lane + 31) & 31);   // left rotate within half-wave (W wraps)
    const int sR = (lane & 32) | ((lane + 1)  & 31);
    const bool act = (l < 26);                         // coef/Jacobi rows: waves 0..12 exactly

    // channel permutation: l<26 -> j=l+3 (coef rows), l=26 -> j=2 (low halo), l=27 -> j=29 (high halo)
    float4 ca0, caE, camx, capx, camy, capy, caS, Dv4, ux4;
    float4 fs = make_float4(0.f, 0.f, 0.f, 0.f);
    int li = 0;

    if (tid < 896) {
        const int j = act ? l + 3 : ((l == 26) ? 2 : 29);
        li = act ? l + 1 : ((l == 26) ? 0 : 27);       // row in g1b / h-buffers (= channel - (c0-6))

        // vector LDS read of the 3x6 bf16 neighborhood (b64+b32 per row)
        float col[3][6];
        #pragma unroll
        for (int r = 0; r < 3; ++r) {
            const unsigned* p = reinterpret_cast<const unsigned*>(&s0s[r][j][w0]);
            unsigned d0 = p[0], d1 = p[1], d2 = p[2];
            col[r][0] = lo16(d0); col[r][1] = hi16(d0);
            col[r][2] = lo16(d1); col[r][3] = hi16(d1);
            col[r][4] = lo16(d2); col[r][5] = hi16(d2);
        }

        // depthwise conv + BN + relu (both filters), 4 cells
        float gvk[4], g1vk[4];
        #pragma unroll
        for (int k = 0; k < 4; ++k) {
            float a = 0.f, a1 = 0.f;
            #pragma unroll
            for (int r = 0; r < 3; ++r)
                #pragma unroll
                for (int dx = 0; dx < 3; ++dx) {
                    float v = col[r][k + dx];
                    a  = fmaf(v, wgt[0][r*3 + dx][j], a);
                    a1 = fmaf(v, wgt[1][r*3 + dx][j], a1);
                }
            a  = fmaf(a,  bnp[0][j], bnp[1][j]);
            a1 = fmaf(a1, bnp[2][j], bnp[3][j]);
            gvk[k]  = fmaxf(a , 0.f);
            g1vk[k] = fmaxf(a1, 0.f);
        }
        *(float4*)&g1b[li*128 + w0] = make_float4(g1vk[0], g1vk[1], g1vk[2], g1vk[3]);

        // W-neighbor g via intra-wave shuffle (circular in W)
        float gL = __shfl(gvk[3], sL);
        float gR = __shfl(gvk[0], sR);

        fs = make_float4(col[1][1], col[1][2], col[1][3], col[1][4]);   // fsrc

        if (act) {
            // reflect overrides for sobel only (conv used the zero pads above)
            #pragma unroll
            for (int r = 0; r < 3; ++r) {
                col[r][0] = (wq == 0)  ? col[r][2] : col[r][0];
                col[r][5] = (wq == 31) ? col[r][3] : col[r][5];
            }
            float gXa[6], dY[6];
            #pragma unroll
            for (int c = 0; c < 6; ++c) {
                gXa[c] = col[0][c] + 2.f*col[1][c] + col[2][c];
                dY[c]  = col[2][c] - col[0][c];
            }
            float fsk[4] = {fs.x, fs.y, fs.z, fs.w};
            float uxk[4] = {0.5f*(gL     - gvk[1]), 0.5f*(gvk[0] - gvk[2]),
                            0.5f*(gvk[1] - gvk[3]), 0.5f*(gvk[2] - gR)};
            float o0[4], omx[4], opx[4], omy[4], opy[4], oS[4], dv[4];
            #pragma unroll
            for (int k = 0; k < 4; ++k) {
                float gy = dY[k] + 2.f*dY[k+1] + dY[k+2];
                float gx = gXa[k+2] - gXa[k];
                float Dx = __builtin_amdgcn_rcpf(fmaf(gy*gy, 0.25f, 1.f));   // 1 ulp rcp, tol 0.0625
                float Dy = __builtin_amdgcn_rcpf(fmaf(gx*gx, 0.25f, 1.f));
                float Bx = Dx*DTC, By = Dy*DTC;
                float s2 = 2.f*(Bx + By);
                float Dv = __builtin_amdgcn_rcpf(1.f + s2);
                float Ax = gvk[k]*DTC, Ay = g1vk[k]*DTC;
                o0[k]  = Dv*(1.f - s2);
                oS[k]  = Dv*(2.f*DTC)*fsk[k];
                omx[k] = Dv*(2.f*Bx - Ax);  opx[k] = Dv*(2.f*Bx + Ax);
                omy[k] = Dv*(2.f*By - Ay);  opy[k] = Dv*(2.f*By + Ay);
                dv[k]  = Dv;
            }
            ca0  = make_float4(o0[0],  o0[1],  o0[2],  o0[3]);
            camx = make_float4(omx[0], omx[1], omx[2], omx[3]);
            capx = make_float4(opx[0], opx[1], opx[2], opx[3]);
            camy = make_float4(omy[0], omy[1], omy[2], omy[3]);
            capy = make_float4(opy[0], opy[1], opy[2], opy[3]);
            caS  = make_float4(oS[0],  oS[1],  oS[2],  oS[3]);
            Dv4  = make_float4(dv[0],  dv[1],  dv[2],  dv[3]);
            ux4  = make_float4(uxk[0], uxk[1], uxk[2], uxk[3]);
        } else {
            // constant-fsrc halo rows for the Jacobi buffers (rows 0 and 27, both buffers)
            *(float4*)&hb0[li*HBS + w0] = fs;
            *(float4*)&hb1[li*HBS + w0] = fs;
        }
    }
    __syncthreads();   // B2: g1b complete

    if (act) {
        float4 g1u = *(float4*)&g1b[(li-1)*128 + w0];   // channel - 1
        float4 g1d = *(float4*)&g1b[(li+1)*128 + w0];   // channel + 1
        caE.x = 2.f*Dv4.x * ((ux4.x + 0.5f*(g1u.x - g1d.x)) * DTC);
        caE.y = 2.f*Dv4.y * ((ux4.y + 0.5f*(g1u.y - g1d.y)) * DTC);
        caE.z = 2.f*Dv4.z * ((ux4.z + 0.5f*(g1u.z - g1d.z)) * DTC);
        caE.w = 2.f*Dv4.w * ((ux4.w + 0.5f*(g1u.w - g1d.w)) * DTC);
    }

    // ---- Jacobi: hc/h0 live in registers; LDS only carries up/dn exchange ----
    float4 h0r = fs, hcr = fs;
    #pragma unroll
    for (int n = 0; n < 5; ++n) {
        float* hb = (n & 1) ? hb1 : hb0;
        if (act) *(float4*)&hb[li*HBS + w0] = hcr;
        __syncthreads();                                   // B3..B7
        if (act) {
            float4 up = *(float4*)&hb[(li-1)*HBS + w0];
            float4 dn = *(float4*)&hb[(li+1)*HBS + w0];
            float eL = __shfl(hcr.w, sL);                  // W-edge neighbors from registers
            float eR = __shfl(hcr.x, sR);
            float4 nw;
            {
                float t = fmaf(ca0.x, h0r.x, caS.x);
                t = fmaf(-caE.x, hcr.x, t);
                t = fmaf(camx.x, eL,    t);
                t = fmaf(capx.x, hcr.y, t);
                t = fmaf(camy.x, up.x,  t);
                nw.x = fmaf(capy.x, dn.x, t);
            }
            {
                float t = fmaf(ca0.y, h0r.y, caS.y);
                t = fmaf(-caE.y, hcr.y, t);
                t = fmaf(camx.y, hcr.x, t);
                t = fmaf(capx.y, hcr.z, t);
                t = fmaf(camy.y, up.y,  t);
                nw.y = fmaf(capy.y, dn.y, t);
            }
            {
                float t = fmaf(ca0.z, h0r.z, caS.z);
                t = fmaf(-caE.z, hcr.z, t);
                t = fmaf(camx.z, hcr.y, t);
                t = fmaf(capx.z, hcr.w, t);
                t = fmaf(camy.z, up.z,  t);
                nw.z = fmaf(capy.z, dn.z, t);
            }
            {
                float t = fmaf(ca0.w, h0r.w, caS.w);
                t = fmaf(-caE.w, hcr.w, t);
                t = fmaf(camx.w, hcr.z, t);
                t = fmaf(capx.w, eR,    t);
                t = fmaf(camy.w, up.w,  t);
                nw.w = fmaf(capy.w, dn.w, t);
            }
            h0r = hcr; hcr = nw;
        }
    }
    // publish final h for the transpose-to-output pass (hb1 last read at n=3 -> safe)
    if (act) *(float4*)&hb1[li*HBS + w0] = hcr;
    __syncthreads();   // B8

    // ---- out = relu(bn(h)) on the 16 core channels (32B-contiguous global chunks) ----
    if (tid < 512) {
        int i16 = tid & 15, w5 = ((tid >> 4) & 31) << 2;
        float4 v = *(float4*)&hb1[(i16 + 6)*HBS + w5];     // HBS=132 -> 2-way (free) bank access
        float sc = obn[0][i16], bi = obn[1][i16];
        size_t ob = (((size_t)b*HN + h)*WN + w5)*CN + (c0 + i16);
        stf(&out[ob],          fmaxf(fmaf(v.x, sc, bi), 0.f));
        stf(&out[ob + CN],     fmaxf(fmaf(v.y, sc, bi), 0.f));
        stf(&out[ob + 2*CN],   fmaxf(fmaf(v.z, sc, bi), 0.f));
        stf(&out[ob + 3*CN],   fmaxf(fmaf(v.w, sc, bi), 0.f));
    }
}

extern "C" void kernel_launch(void* const* d_in, const int* in_sizes, int n_in,
                              void* d_out, int out_size, void* d_ws, size_t ws_size,
                              hipStream_t stream) {
    dim3 grid(BN * 16 * HN);   // 16384 blocks

    if (ws_size >= 4) {
        int* flag = (int*)d_ws;
        probe_kernel<<<1, 256, 0, stream>>>((const unsigned int*)d_in[0], flag);

        diffusion_kernel<float><<<grid, NTH, 0, stream>>>(
            (const float*)d_in[0], (const float*)d_in[1], (const float*)d_in[2],
            (const float*)d_in[3], (const float*)d_in[4], (const float*)d_in[5], (const float*)d_in[6],
            (const float*)d_in[7], (const float*)d_in[8], (const float*)d_in[9], (const float*)d_in[10],
            (const float*)d_in[11], (const float*)d_in[12], (const float*)d_in[13], (const float*)d_in[14],
            (float*)d_out, flag, 0);

        diffusion_kernel<__hip_bfloat16><<<grid, NTH, 0, stream>>>(
            (const __hip_bfloat16*)d_in[0], (const __hip_bfloat16*)d_in[1], (const __hip_bfloat16*)d_in[2],
            (const __hip_bfloat16*)d_in[3], (const __hip_bfloat16*)d_in[4], (const __hip_bfloat16*)d_in[5], (const __hip_bfloat16*)d_in[6],
            (const __hip_bfloat16*)d_in[7], (const __hip_bfloat16*)d_in[8], (const __hip_bfloat16*)d_in[9], (const __hip_bfloat16*)d_in[10],
            (const __hip_bfloat16*)d_in[11], (const __hip_bfloat16*)d_in[12], (const __hip_bfloat16*)d_in[13], (const __hip_bfloat16*)d_in[14],
            (__hip_bfloat16*)d_out, flag, 1);
    } else {
        diffusion_kernel<float><<<grid, NTH, 0, stream>>>(
            (const float*)d_in[0], (const float*)d_in[1], (const float*)d_in[2],
            (const float*)d_in[3], (const float*)d_in[4], (const float*)d_in[5], (const float*)d_in[6],
            (const float*)d_in[7], (const float*)d_in[8], (const float*)d_in[9], (const float*)d_in[10],
            (const float*)d_in[11], (const float*)d_in[12], (const float*)d_in[13], (const float*)d_in[14],
            (float*)d_out, nullptr, 0);
    }
}

// Round 2
// 648.868 us; speedup vs baseline: 1.4139x; 1.4139x over previous
//
#include <hip/hip_runtime.h>
#include <hip/hip_bf16.h>

#define BN 8
#define HN 128
#define WN 128
#define CN 256
#define DTC 0.2f
#define EPSV 1e-3f
#define NTH 1024

#define SW 136     // s0s w-stride (halfs): col0/col129 zero pads, data 1..128, 130..135 unused (16B row align)
#define HBS 132    // h-buffer row stride (floats): 132 ≡ 4 mod 32 banks → de-conflicts pass-5 column reads

// ---- dtype-generic helpers (compute stays f32) ----
__device__ __forceinline__ float ldf(const float* p)            { return *p; }
__device__ __forceinline__ float ldf(const __hip_bfloat16* p)   { return __bfloat162float(*p); }
__device__ __forceinline__ void stf(float* p, float v)          { *p = v; }
__device__ __forceinline__ void stf(__hip_bfloat16* p, float v) { *p = __float2bfloat16(v); }

// packed bf16 extraction (exact f32)
__device__ __forceinline__ float lo16(unsigned u){ return __uint_as_float(u << 16); }
__device__ __forceinline__ float hi16(unsigned u){ return __uint_as_float(u & 0xffff0000u); }

// stage 4 consecutive channels (one vector load) into 4 LDS channel-rows
__device__ __forceinline__ void stage4(__hip_bfloat16* dp, const __hip_bfloat16* gp) {
    ushort4 v = *reinterpret_cast<const ushort4*>(gp);
    unsigned short* d = reinterpret_cast<unsigned short*>(dp);
    d[0] = v.x; d[SW] = v.y; d[2*SW] = v.z; d[3*SW] = v.w;
}
__device__ __forceinline__ void stage4(__hip_bfloat16* dp, const float* gp) {
    float4 v = *reinterpret_cast<const float4*>(gp);
    dp[0]    = __float2bfloat16(v.x);
    dp[SW]   = __float2bfloat16(v.y);
    dp[2*SW] = __float2bfloat16(v.z);
    dp[3*SW] = __float2bfloat16(v.w);
}

// ---- dtype probe: bf16 exponent band test on raw u32 words ----
__global__ void probe_kernel(const unsigned int* __restrict__ s0w, int* __restrict__ flag) {
    __shared__ int cnt;
    if (threadIdx.x == 0) cnt = 0;
    __syncthreads();
    int local = 0;
    for (int i = threadIdx.x; i < 4096; i += 256) {
        unsigned int e = (s0w[i] >> 7) & 0xFF;
        if (e >= 118 && e <= 130) local++;
    }
    atomicAdd(&cnt, local);
    __syncthreads();
    if (threadIdx.x == 0) *flag = (cnt > 2048) ? 1 : 0;   // 1 = bf16, 0 = f32
}

template <typename T>
__global__ __launch_bounds__(NTH, 4)   // min 4 waves/EU -> VGPR cap 128, NO SPILLS (r1 post-mortem)
void diffusion_kernel(const T* __restrict__ s0,  const T* __restrict__ wg,  const T* __restrict__ wg1,
                      const T* __restrict__ g_gamma,  const T* __restrict__ g_beta,
                      const T* __restrict__ g_mean,   const T* __restrict__ g_var,
                      const T* __restrict__ g1_gamma, const T* __restrict__ g1_beta,
                      const T* __restrict__ g1_mean,  const T* __restrict__ g1_var,
                      const T* __restrict__ out_gamma, const T* __restrict__ out_beta,
                      const T* __restrict__ out_mean,  const T* __restrict__ out_var,
                      T* __restrict__ out,
                      const int* __restrict__ flag, int want)
{
    if (flag && *flag != want) return;   // dtype dispatch

    __shared__ __align__(16) __hip_bfloat16 s0s[3][32][SW];  // 26112 B
    __shared__ float wgt[2][9][32];                          //  2304 B
    __shared__ float bnp[4][32];                             //   512 B
    __shared__ float obn[2][16];                             //   128 B
    __shared__ __align__(16) float g1b[28*128];              // 14336 B
    __shared__ __align__(16) float hb0[28*HBS];              // 14784 B
    __shared__ __align__(16) float hb1[28*HBS];              // 14784 B
    // total 72960 B

    const int tid = threadIdx.x;
    const int bid = blockIdx.x;
    const int h     = bid & 127;
    const int bc    = bid >> 7;
    const int chunk = bc & 15;
    const int b     = bc >> 4;
    const int c0    = chunk << 4;

    const int   rT   = (h > 0)   ? h - 1 : 1;      // sobel reflect rows
    const int   rB   = (h < 127) ? h + 1 : 126;
    const float topf = (h > 0)   ? 1.f : 0.f;      // conv zero-pad flags (folded into weights)
    const float botf = (h < 127) ? 1.f : 0.f;

    // ---- stage s0: 3 rows x 32 ch x 128 w; 4-channel vector loads (3072 total, 3/thread) ----
    {
        const size_t base = (size_t)b * HN * WN * CN;
        #pragma unroll
        for (int k = 0; k < 3; ++k) {
            int e  = tid + k * NTH;                // < 3072
            int j4 = e & 7;                        // 4-channel group
            int w  = (e >> 3) & 127;
            int r  = e >> 10;                      // 0..2
            int row = (r == 0) ? rT : ((r == 1) ? h : rB);
            int cj  = (c0 - 8 + (j4 << 2)) & 255;  // group never straddles the wrap (4-aligned)
            stage4(&s0s[r][j4 << 2][w + 1], &s0[base + ((size_t)row * WN + w) * CN + cj]);
        }
    }
    if (tid < 192) {                               // zero pad columns (conv SAME)
        int r = tid >> 6, j = (tid >> 1) & 31, cp = (tid & 1) ? 129 : 0;
        s0s[r][j][cp] = __float2bfloat16(0.f);
    }
    if (tid < 288) {                               // weights, H-pad folded in
        int t9 = tid >> 5, j = tid & 31;
        int cj = (c0 - 8 + j) & 255;
        float rf = (t9 < 3) ? topf : ((t9 >= 6) ? botf : 1.f);
        wgt[0][t9][j] = ldf(&wg [t9*CN + cj]) * rf;
        wgt[1][t9][j] = ldf(&wg1[t9*CN + cj]) * rf;
    }
    if (tid < 32) {                                // folded BN params
        int cj = (c0 - 8 + tid) & 255;
        float s  = ldf(&g_gamma[cj])  * rsqrtf(ldf(&g_var[cj])  + EPSV);
        bnp[0][tid] = s;
        bnp[1][tid] = ldf(&g_beta[cj])  - ldf(&g_mean[cj])  * s;
        float s1 = ldf(&g1_gamma[cj]) * rsqrtf(ldf(&g1_var[cj]) + EPSV);
        bnp[2][tid] = s1;
        bnp[3][tid] = ldf(&g1_beta[cj]) - ldf(&g1_mean[cj]) * s1;
    }
    if (tid < 16) {
        int c = c0 + tid;
        float s = ldf(&out_gamma[c]) * rsqrtf(ldf(&out_var[c]) + EPSV);
        obn[0][tid] = s;
        obn[1][tid] = ldf(&out_beta[c]) - ldf(&out_mean[c]) * s;
    }
    __syncthreads();   // B1

    // thread geometry: half-wave = one channel row, wq = quad index in W
    const int wq = tid & 31, l = tid >> 5, w0 = wq << 2;
    const int lane = tid & 63;
    const int sL = (lane & 32) | ((lane + 31) & 31);   // left rotate within half-wave (W wraps)
    const int sR = (lane & 32) | ((lane + 1)  & 31);
    const bool act = (l < 26);                         // coef/Jacobi rows: waves 0..12 exactly

    // channel permutation: l<26 -> j=l+3 (coef rows), l=26 -> j=2 (low halo), l=27 -> j=29 (high halo)
    float4 ca0, caE, camx, capx, camy, capy, caS, bs4;
    float4 fs = make_float4(0.f, 0.f, 0.f, 0.f);
    int li = 0;

    if (tid < 896) {
        const int j = act ? l + 3 : ((l == 26) ? 2 : 29);
        li = act ? l + 1 : ((l == 26) ? 0 : 27);       // row in g1b / h-buffers (= channel - (c0-6))

        // vector LDS read of the 3x6 bf16 neighborhood (b64+b32 per row)
        float col[3][6];
        #pragma unroll
        for (int r = 0; r < 3; ++r) {
            const unsigned* p = reinterpret_cast<const unsigned*>(&s0s[r][j][w0]);
            unsigned d0 = p[0], d1 = p[1], d2 = p[2];
            col[r][0] = lo16(d0); col[r][1] = hi16(d0);
            col[r][2] = lo16(d1); col[r][3] = hi16(d1);
            col[r][4] = lo16(d2); col[r][5] = hi16(d2);
        }

        // depthwise conv + BN + relu (both filters), 4 cells
        float gvk[4], g1vk[4];
        #pragma unroll
        for (int k = 0; k < 4; ++k) {
            float a = 0.f, a1 = 0.f;
            #pragma unroll
            for (int r = 0; r < 3; ++r)
                #pragma unroll
                for (int dx = 0; dx < 3; ++dx) {
                    float v = col[r][k + dx];
                    a  = fmaf(v, wgt[0][r*3 + dx][j], a);
                    a1 = fmaf(v, wgt[1][r*3 + dx][j], a1);
                }
            a  = fmaf(a,  bnp[0][j], bnp[1][j]);
            a1 = fmaf(a1, bnp[2][j], bnp[3][j]);
            gvk[k]  = fmaxf(a , 0.f);
            g1vk[k] = fmaxf(a1, 0.f);
        }
        *(float4*)&g1b[li*128 + w0] = make_float4(g1vk[0], g1vk[1], g1vk[2], g1vk[3]);

        // W-neighbor g via intra-wave shuffle (circular in W)
        float gL = __shfl(gvk[3], sL);
        float gR = __shfl(gvk[0], sR);

        fs = make_float4(col[1][1], col[1][2], col[1][3], col[1][4]);   // fsrc

        if (act) {
            // reflect overrides for sobel only (conv used the zero pads above)
            #pragma unroll
            for (int r = 0; r < 3; ++r) {
                col[r][0] = (wq == 0)  ? col[r][2] : col[r][0];
                col[r][5] = (wq == 31) ? col[r][3] : col[r][5];
            }
            float gXa[6], dY[6];
            #pragma unroll
            for (int c = 0; c < 6; ++c) {
                gXa[c] = col[0][c] + 2.f*col[1][c] + col[2][c];
                dY[c]  = col[2][c] - col[0][c];
            }
            float fsk[4] = {fs.x, fs.y, fs.z, fs.w};
            float uxk[4] = {0.5f*(gL     - gvk[1]), 0.5f*(gvk[0] - gvk[2]),
                            0.5f*(gvk[1] - gvk[3]), 0.5f*(gvk[2] - gR)};
            float o0[4], omx[4], opx[4], omy[4], opy[4], oS[4], oE[4], bsk[4];
            #pragma unroll
            for (int k = 0; k < 4; ++k) {
                float gy = dY[k] + 2.f*dY[k+1] + dY[k+2];
                float gx = gXa[k+2] - gXa[k];
                float Dx = __builtin_amdgcn_rcpf(fmaf(gy*gy, 0.25f, 1.f));   // 1 ulp rcp, tol 0.0625
                float Dy = __builtin_amdgcn_rcpf(fmaf(gx*gx, 0.25f, 1.f));
                float Bx = Dx*DTC, By = Dy*DTC;
                float s2 = 2.f*(Bx + By);
                float Dv = __builtin_amdgcn_rcpf(1.f + s2);
                float Ax = gvk[k]*DTC, Ay = g1vk[k]*DTC;
                o0[k]  = Dv*(1.f - s2);
                oS[k]  = Dv*(2.f*DTC)*fsk[k];
                omx[k] = Dv*(2.f*Bx - Ax);  opx[k] = Dv*(2.f*Bx + Ax);
                omy[k] = Dv*(2.f*By - Ay);  opy[k] = Dv*(2.f*By + Ay);
                bsk[k] = Dv*DTC;                     // scale for (g1u - g1d) term of caE
                oE[k]  = 2.f*bsk[k]*uxk[k];          // caE partial: 2*Dv*DTC*ux
            }
            ca0  = make_float4(o0[0],  o0[1],  o0[2],  o0[3]);
            camx = make_float4(omx[0], omx[1], omx[2], omx[3]);
            capx = make_float4(opx[0], opx[1], opx[2], opx[3]);
            camy = make_float4(omy[0], omy[1], omy[2], omy[3]);
            capy = make_float4(opy[0], opy[1], opy[2], opy[3]);
            caS  = make_float4(oS[0],  oS[1],  oS[2],  oS[3]);
            caE  = make_float4(oE[0],  oE[1],  oE[2],  oE[3]);
            bs4  = make_float4(bsk[0], bsk[1], bsk[2], bsk[3]);
        } else {
            // constant-fsrc halo rows for the Jacobi buffers (rows 0 and 27, both buffers)
            *(float4*)&hb0[li*HBS + w0] = fs;
            *(float4*)&hb1[li*HBS + w0] = fs;
        }
    }
    __syncthreads();   // B2: g1b complete

    if (act) {
        float4 g1u = *(float4*)&g1b[(li-1)*128 + w0];   // channel - 1
        float4 g1d = *(float4*)&g1b[(li+1)*128 + w0];   // channel + 1
        // caE = 2*Dv*Ev = 2*Dv*DTC*ux + Dv*DTC*(g1u - g1d)
        caE.x = fmaf(bs4.x, g1u.x - g1d.x, caE.x);
        caE.y = fmaf(bs4.y, g1u.y - g1d.y, caE.y);
        caE.z = fmaf(bs4.z, g1u.z - g1d.z, caE.z);
        caE.w = fmaf(bs4.w, g1u.w - g1d.w, caE.w);
    }

    // ---- Jacobi: hc/h0 live in registers; LDS only carries up/dn exchange ----
    float4 h0r = fs, hcr = fs;
    #pragma unroll
    for (int n = 0; n < 5; ++n) {
        float* hb = (n & 1) ? hb1 : hb0;
        if (act) *(float4*)&hb[li*HBS + w0] = hcr;
        __syncthreads();                                   // B3..B7
        if (act) {
            float4 up = *(float4*)&hb[(li-1)*HBS + w0];
            float4 dn = *(float4*)&hb[(li+1)*HBS + w0];
            float eL = __shfl(hcr.w, sL);                  // W-edge neighbors from registers
            float eR = __shfl(hcr.x, sR);
            float4 nw;
            {
                float t = fmaf(ca0.x, h0r.x, caS.x);
                t = fmaf(-caE.x, hcr.x, t);
                t = fmaf(camx.x, eL,    t);
                t = fmaf(capx.x, hcr.y, t);
                t = fmaf(camy.x, up.x,  t);
                nw.x = fmaf(capy.x, dn.x, t);
            }
            {
                float t = fmaf(ca0.y, h0r.y, caS.y);
                t = fmaf(-caE.y, hcr.y, t);
                t = fmaf(camx.y, hcr.x, t);
                t = fmaf(capx.y, hcr.z, t);
                t = fmaf(camy.y, up.y,  t);
                nw.y = fmaf(capy.y, dn.y, t);
            }
            {
                float t = fmaf(ca0.z, h0r.z, caS.z);
                t = fmaf(-caE.z, hcr.z, t);
                t = fmaf(camx.z, hcr.y, t);
                t = fmaf(capx.z, hcr.w, t);
                t = fmaf(camy.z, up.z,  t);
                nw.z = fmaf(capy.z, dn.z, t);
            }
            {
                float t = fmaf(ca0.w, h0r.w, caS.w);
                t = fmaf(-caE.w, hcr.w, t);
                t = fmaf(camx.w, hcr.z, t);
                t = fmaf(capx.w, eR,    t);
                t = fmaf(camy.w, up.w,  t);
                nw.w = fmaf(capy.w, dn.w, t);
            }
            h0r = hcr; hcr = nw;
        }
    }
    // publish final h for the transpose-to-output pass (hb1 last read at n=3 -> safe)
    if (act) *(float4*)&hb1[li*HBS + w0] = hcr;
    __syncthreads();   // B8

    // ---- out = relu(bn(h)) on the 16 core channels (32B-contiguous global chunks) ----
    if (tid < 512) {
        int i16 = tid & 15, w5 = ((tid >> 4) & 31) << 2;
        float4 v = *(float4*)&hb1[(i16 + 6)*HBS + w5];     // HBS=132 -> 2-way (free) bank access
        float sc = obn[0][i16], bi = obn[1][i16];
        size_t ob = (((size_t)b*HN + h)*WN + w5)*CN + (c0 + i16);
        stf(&out[ob],          fmaxf(fmaf(v.x, sc, bi), 0.f));
        stf(&out[ob + CN],     fmaxf(fmaf(v.y, sc, bi), 0.f));
        stf(&out[ob + 2*CN],   fmaxf(fmaf(v.z, sc, bi), 0.f));
        stf(&out[ob + 3*CN],   fmaxf(fmaf(v.w, sc, bi), 0.f));
    }
}

extern "C" void kernel_launch(void* const* d_in, const int* in_sizes, int n_in,
                              void* d_out, int out_size, void* d_ws, size_t ws_size,
                              hipStream_t stream) {
    dim3 grid(BN * 16 * HN);   // 16384 blocks

    if (ws_size >= 4) {
        int* flag = (int*)d_ws;
        probe_kernel<<<1, 256, 0, stream>>>((const unsigned int*)d_in[0], flag);

        diffusion_kernel<float><<<grid, NTH, 0, stream>>>(
            (const float*)d_in[0], (const float*)d_in[1], (const float*)d_in[2],
            (const float*)d_in[3], (const float*)d_in[4], (const float*)d_in[5], (const float*)d_in[6],
            (const float*)d_in[7], (const float*)d_in[8], (const float*)d_in[9], (const float*)d_in[10],
            (const float*)d_in[11], (const float*)d_in[12], (const float*)d_in[13], (const float*)d_in[14],
            (float*)d_out, flag, 0);

        diffusion_kernel<__hip_bfloat16><<<grid, NTH, 0, stream>>>(
            (const __hip_bfloat16*)d_in[0], (const __hip_bfloat16*)d_in[1], (const __hip_bfloat16*)d_in[2],
            (const __hip_bfloat16*)d_in[3], (const __hip_bfloat16*)d_in[4], (const __hip_bfloat16*)d_in[5], (const __hip_bfloat16*)d_in[6],
            (const __hip_bfloat16*)d_in[7], (const __hip_bfloat16*)d_in[8], (const __hip_bfloat16*)d_in[9], (const __hip_bfloat16*)d_in[10],
            (const __hip_bfloat16*)d_in[11], (const __hip_bfloat16*)d_in[12], (const __hip_bfloat16*)d_in[13], (const __hip_bfloat16*)d_in[14],
            (__hip_bfloat16*)d_out, flag, 1);
    } else {
        diffusion_kernel<float><<<grid, NTH, 0, stream>>>(
            (const float*)d_in[0], (const float*)d_in[1], (const float*)d_in[2],
            (const float*)d_in[3], (const float*)d_in[4], (const float*)d_in[5], (const float*)d_in[6],
            (const float*)d_in[7], (const float*)d_in[8], (const float*)d_in[9], (const float*)d_in[10],
            (const float*)d_in[11], (const float*)d_in[12], (const float*)d_in[13], (const float*)d_in[14],
            (float*)d_out, nullptr, 0);
    }
}